// Round 13
// baseline (171.443 us; speedup 1.0000x reference)
//
#include <hip/hip_runtime.h>

#define NPIX 9216
#define CIN 72
#define CP 96
#define SPLITS 8
#define JCHUNK (NPIX / SPLITS)   // 1152
#define JTILES (JCHUNK / 64)     // 18
// p = exp2(s*log2e - 32*log2e)  (fixed softmax shift 32; safe to s<120)
#define L2E   1.44269504088896f
#define EXPB  46.1662413084468f

typedef __attribute__((ext_vector_type(8))) short bf16x8;
typedef __attribute__((ext_vector_type(8))) _Float16 f16x8;
typedef __attribute__((ext_vector_type(4))) float f32x4;

#define MFMA_BF16(A,B,C) __builtin_amdgcn_mfma_f32_16x16x32_bf16(A,B,C,0,0,0)
#define MFMA_F16(A,B,C)  __builtin_amdgcn_mfma_f32_16x16x32_f16(A,B,C,0,0,0)

static __device__ __forceinline__ unsigned short f2bf(float f) {
  unsigned u = __float_as_uint(f);
  u += 0x7fffu + ((u >> 16) & 1u);
  return (unsigned short)(u >> 16);
}
static __device__ __forceinline__ float bf2f(unsigned short h) {
  return __uint_as_float(((unsigned)h) << 16);
}
static __device__ __forceinline__ unsigned short f2h(float f) {
  _Float16 h = (_Float16)f;
  return *(unsigned short*)&h;
}
// pack trunc-bf16 of (lo,hi) into one dword: [lo.hi16 | hi.hi16]
static __device__ __forceinline__ unsigned pack_bf_trunc(float lo, float hi) {
  return (__float_as_uint(lo) >> 16) | (__float_as_uint(hi) & 0xffff0000u);
}

// ---------------------------------------------------------------------------
// Kernel 0: W prep — split-bf16 (hi/lo) of Wq/Wk/Wv, padded to [80][96].
// ---------------------------------------------------------------------------
__global__ __launch_bounds__(256) void wprep_kernel(
    const float* __restrict__ Wq, const float* __restrict__ Wk,
    const float* __restrict__ Wv,
    unsigned short* __restrict__ WH, unsigned short* __restrict__ WL)
{
  int id = blockIdx.x * 256 + threadIdx.x;
  if (id >= 3 * 80 * 96) return;
  int mat = id / (80 * 96);
  int rem = id % (80 * 96);
  int d = rem / 96, c = rem % 96;
  const float* W = (mat == 0) ? Wq : (mat == 1) ? Wk : Wv;
  float v = (d < 72 && c < 72) ? W[d * 72 + c] : 0.f;
  unsigned short hi = f2bf(v);
  WH[id] = hi;
  WL[id] = f2bf(v - bf2f(hi));
}

// ---------------------------------------------------------------------------
// Kernel 1: QKV projection, split-bf16 MFMA GEMM, one wave per block (16 px).
// V channel 72 = 1.0 (ones-row): flash PV then computes L for free.
// ---------------------------------------------------------------------------
#define XTS 104   // LDS row stride (ushorts), 208 B

__global__ __launch_bounds__(64) void qkv_kernel(
    const float* __restrict__ x,
    const unsigned short* __restrict__ WH, const unsigned short* __restrict__ WL,
    const float* __restrict__ bq, const float* __restrict__ bk,
    const float* __restrict__ bv,
    unsigned short* __restrict__ QH, unsigned short* __restrict__ KH,
    unsigned short* __restrict__ VG)
{
  __shared__ __align__(16) unsigned short xth[16 * XTS];
  __shared__ __align__(16) unsigned short xtl[16 * XTS];
  __shared__ __align__(16) unsigned short obuf[16 * XTS];

  const int t    = threadIdx.x;
  const int quad = t >> 4;
  const int l15  = t & 15;
  const int bid  = blockIdx.x;
  const int b    = bid / 576;
  const int n0   = (bid % 576) * 16;

  // stage X strip, float4 global loads, split-bf16, transposed to [px][c]
  for (int e = t; e < 288; e += 64) {
    int c = e >> 2, f4 = (e & 3) * 4;
    float4 xv = *(const float4*)(x + ((size_t)b * CIN + c) * NPIX + n0 + f4);
    float vv[4] = {xv.x, xv.y, xv.z, xv.w};
#pragma unroll
    for (int k = 0; k < 4; ++k) {
      unsigned short hi = f2bf(vv[k]);
      xth[(f4 + k) * XTS + c] = hi;
      xtl[(f4 + k) * XTS + c] = f2bf(vv[k] - bf2f(hi));
    }
  }
  for (int e = t; e < 24 * 16; e += 64) {
    int c = 72 + (e >> 4), px = e & 15;
    xth[px * XTS + c] = 0;
    xtl[px * XTS + c] = 0;
  }
  __syncthreads();

  bf16x8 xbh[3], xbl[3];
#pragma unroll
  for (int ks = 0; ks < 3; ++ks) {
    int off = l15 * XTS + ks * 32 + quad * 8;
    xbh[ks] = *(const bf16x8*)(xth + off);
    xbl[ks] = *(const bf16x8*)(xtl + off);
  }

  for (int mat = 0; mat < 3; ++mat) {
    const unsigned short* wh = WH + mat * 80 * 96;
    const unsigned short* wl = WL + mat * 80 * 96;
    const float* bias = (mat == 0) ? bq : (mat == 1) ? bk : bv;

    f32x4 acc[5];
#pragma unroll
    for (int dm = 0; dm < 5; ++dm) {
      acc[dm] = (f32x4){0.f, 0.f, 0.f, 0.f};
#pragma unroll
      for (int ks = 0; ks < 3; ++ks) {
        bf16x8 ah = *(const bf16x8*)(wh + (dm * 16 + l15) * 96 + ks * 32 + quad * 8);
        bf16x8 al = *(const bf16x8*)(wl + (dm * 16 + l15) * 96 + ks * 32 + quad * 8);
        acc[dm] = MFMA_BF16(ah, xbh[ks], acc[dm]);
        acc[dm] = MFMA_BF16(ah, xbl[ks], acc[dm]);
        acc[dm] = MFMA_BF16(al, xbh[ks], acc[dm]);
      }
    }

    if (mat < 2) {
      __syncthreads();                 // obuf free
#pragma unroll
      for (int dm = 0; dm < 5; ++dm)
#pragma unroll
        for (int r = 0; r < 4; ++r) {
          int d = dm * 16 + quad * 4 + r;
          float v = acc[dm][r] + (d < 72 ? bias[d] : 0.f);
          obuf[l15 * XTS + d] = f2h(v);
        }
      __syncthreads();
      unsigned short* outp = (mat == 0) ? QH : KH;
      const size_t ob = ((size_t)b * NPIX + n0) * CP;
      uint4 z; z.x = z.y = z.z = z.w = 0u;
      for (int f = t; f < 192; f += 64) {
        int row = f / 12, col = f % 12;
        *(uint4*)(outp + ob + (size_t)row * CP + col * 8) =
            (col < 10) ? *(const uint4*)(obuf + row * XTS + col * 8) : z;
      }
    } else {
#pragma unroll
      for (int dm = 0; dm < 5; ++dm)
#pragma unroll
        for (int r = 0; r < 4; ++r) {
          int d = dm * 16 + quad * 4 + r;
          float v = (d < 72) ? acc[dm][r] + bias[d] : (d == 72 ? 1.0f : 0.f);
          VG[((size_t)b * 80 + d) * NPIX + n0 + l15] = f2bf(v);
        }
    }
  }
}

// ---------------------------------------------------------------------------
// Kernel 2: fused flash attention + pooling epilogue.
// K staging: MANUAL at KSP=104 (208B rows -> 8 distinct bank-starts/phase ->
// 2-way = free, for both the staging writes and the fkh A-fragment reads).
// R12's DMA forced KSP=96 (192B) -> only 2 bank-starts -> 8-way on every fkh
// read (~2.9x) — this round isolates that variable. Fused pooling epilogue
// kept from R12 (NUM fp32, no O bf16 round-trip).
// O^T PV with ones-row L (R11). Grid 768; 4 waves x 48 rows; waves=3.
// ---------------------------------------------------------------------------
#define KSP 104   // k tile stride (ushorts) — 2-way-free reads & writes
#define VSP 72    // v tile stride
#define PSP 72    // p tile stride

__global__ __launch_bounds__(256, 3) void flash_kernel(
    const float* __restrict__ x,
    const unsigned short* __restrict__ QH, const unsigned short* __restrict__ KH,
    const unsigned short* __restrict__ VG,
    float* __restrict__ NUM, float* __restrict__ LPART)
{
  __shared__ __align__(16) unsigned short ls_kh[64 * KSP];   // 13,312 B
  __shared__ __align__(16) unsigned short ls_vs[80 * VSP];   // 11,520 B
  __shared__ __align__(16) unsigned short ps[4][48 * PSP];   // 27,648 B
  // total 52,480 B -> 3 blocks/CU

  const int t    = threadIdx.x;
  const int w    = t >> 6;
  const int lane = t & 63;
  const int quad = lane >> 4;
  const int l15  = lane & 15;

  const int bid  = blockIdx.x;
  const int sp   = bid & 7;          // split == XCD id (round-robin dispatch)
  const int slot = bid >> 3;
  const int b    = slot / 48;
  const int it   = slot % 48;
  const int i0w  = it * 192 + w * 48;

  // Q fragments (B-operand of S^T scores: n=l15=i, k=quad*8+c)
  f16x8 qh[3][3];
#pragma unroll
  for (int mi = 0; mi < 3; ++mi)
#pragma unroll
    for (int ks = 0; ks < 3; ++ks) {
      size_t off = ((size_t)b * NPIX + i0w + mi * 16 + l15) * CP + ks * 32 + quad * 8;
      qh[mi][ks] = *(const f16x8*)(QH + off);
    }

  f32x4 oacc[3][5];   // O^T[c][i]: c = nt*16+quad*4+r, i = mi*16+l15
#pragma unroll
  for (int mi = 0; mi < 3; ++mi)
#pragma unroll
    for (int nt = 0; nt < 5; ++nt) oacc[mi][nt] = (f32x4){0.f, 0.f, 0.f, 0.f};

  unsigned short* psw = ps[w];

  const unsigned short* kpg = KH + ((size_t)b * NPIX + sp * JCHUNK) * CP;
  const unsigned short* vpg = VG + (size_t)b * 80 * NPIX + sp * JCHUNK;

  for (int jt = 0; jt < JTILES; ++jt, kpg += 64 * CP, vpg += 64) {
    // ---- stage K and V tiles into LDS (manual, conflict-free patterns) ----
    for (int idx = t; idx < 768; idx += 256) {
      int r = idx / 12, c = idx % 12;
      *(uint4*)(ls_kh + r * KSP + c * 8) = *(const uint4*)(kpg + r * CP + c * 8);
    }
    for (int idx = t; idx < 640; idx += 256) {
      int r = idx >> 3, c = idx & 7;
      *(uint4*)(ls_vs + r * VSP + c * 8) =
          *(const uint4*)(vpg + (size_t)r * NPIX + c * 8);
    }
    __syncthreads();

    // ---- S^T scores (K from LDS) -> exp -> packed b64 P write ----
#pragma unroll
    for (int tj = 0; tj < 4; ++tj) {
      f16x8 fkh[3];
#pragma unroll
      for (int ks = 0; ks < 3; ++ks)
        fkh[ks] = *(const f16x8*)(ls_kh + (tj * 16 + l15) * KSP + ks * 32 + quad * 8);
#pragma unroll
      for (int mi = 0; mi < 3; ++mi) {
        f32x4 s = (f32x4){0.f, 0.f, 0.f, 0.f};
        s = MFMA_F16(fkh[0], qh[mi][0], s);   // A=K (m=j), B=Q (n=i)
        s = MFMA_F16(fkh[1], qh[mi][1], s);
        s = MFMA_F16(fkh[2], qh[mi][2], s);
        float p0 = __builtin_amdgcn_exp2f(__builtin_fmaf(s[0], L2E, -EXPB));
        float p1 = __builtin_amdgcn_exp2f(__builtin_fmaf(s[1], L2E, -EXPB));
        float p2 = __builtin_amdgcn_exp2f(__builtin_fmaf(s[2], L2E, -EXPB));
        float p3 = __builtin_amdgcn_exp2f(__builtin_fmaf(s[3], L2E, -EXPB));
        uint2 pk;
        pk.x = pack_bf_trunc(p0, p1);
        pk.y = pack_bf_trunc(p2, p3);
        *(uint2*)(psw + (mi * 16 + l15) * PSP + tj * 16 + quad * 4) = pk;
      }
    }

    // ---- PV as O^T: A = V (LDS, m=c incl. ones-row 72), B = P (own-wave) ----
#pragma unroll
    for (int js = 0; js < 2; ++js) {
      bf16x8 pf[3];
#pragma unroll
      for (int mi = 0; mi < 3; ++mi)
        pf[mi] = *(const bf16x8*)(psw + (mi * 16 + l15) * PSP + js * 32 + quad * 8);
#pragma unroll
      for (int nt = 0; nt < 5; ++nt) {
        bf16x8 vf = *(const bf16x8*)(ls_vs + (nt * 16 + l15) * VSP + js * 32 + quad * 8);
#pragma unroll
        for (int mi = 0; mi < 3; ++mi)
          oacc[mi][nt] = MFMA_BF16(vf, pf[mi], oacc[mi][nt]);
      }
    }
    __syncthreads();   // all K/V LDS reads done before next staging
  }

  // ---- epilogue: L from ones-row; fused factor-4 pooling -> NUM fp32 ----
  const size_t sb = (size_t)(sp * 2 + b);
#pragma unroll
  for (int mi = 0; mi < 3; ++mi) {
    const int i = i0w + mi * 16 + l15;
    if (quad == 2)   // c = 72: the ones-row -> L
      LPART[sb * NPIX + i] = oacc[mi][4][0];
#pragma unroll
    for (int nt = 0; nt < 5; ++nt) {
      int c0 = nt * 16 + quad * 4;
      if (c0 < 72) {
        float num = 0.f;
#pragma unroll
        for (int r = 0; r < 4; ++r)
          num = __builtin_fmaf(x[((size_t)b * CIN + c0 + r) * NPIX + i],
                               oacc[mi][nt][r], num);
        NUM[(sb * 18 + (c0 >> 2)) * NPIX + i] = num;   // g = nt*4+quad
      }
    }
  }
}

// ---------------------------------------------------------------------------
// Kernel 3: combine splits: out = (sum_s NUM_s) / (sum_s L_s). Trivial.
// ---------------------------------------------------------------------------
__global__ __launch_bounds__(256) void combine_pool_kernel(
    const float* __restrict__ NUM, const float* __restrict__ LPART,
    float* __restrict__ out)
{
  int id = blockIdx.x * 256 + threadIdx.x;
  if (id >= 2 * 18 * (NPIX / 4)) return;
  int n = (id % (NPIX / 4)) * 4;
  int rest = id / (NPIX / 4);       // = b*18 + g
  int g = rest % 18, b = rest / 18;

  float4 A = make_float4(0.f, 0.f, 0.f, 0.f);
  float4 L = make_float4(0.f, 0.f, 0.f, 0.f);
#pragma unroll
  for (int s = 0; s < SPLITS; ++s) {
    size_t sb = (size_t)(s * 2 + b);
    float4 a = *(const float4*)(NUM + (sb * 18 + g) * NPIX + n);
    float4 l = *(const float4*)(LPART + sb * NPIX + n);
    A.x += a.x; A.y += a.y; A.z += a.z; A.w += a.w;
    L.x += l.x; L.y += l.y; L.z += l.z; L.w += l.w;
  }
  float4 r;
  r.x = A.x / L.x; r.y = A.y / L.y; r.z = A.z / L.z; r.w = A.w / L.w;
  *(float4*)(out + (size_t)id * 4) = r;
}

// ---------------------------------------------------------------------------
extern "C" void kernel_launch(void* const* d_in, const int* in_sizes, int n_in,
                              void* d_out, int out_size, void* d_ws, size_t ws_size,
                              hipStream_t stream) {
  const float* x  = (const float*)d_in[0];
  const float* Wq = (const float*)d_in[1];
  const float* bq = (const float*)d_in[2];
  const float* Wk = (const float*)d_in[3];
  const float* bk = (const float*)d_in[4];
  const float* Wv = (const float*)d_in[5];
  const float* bv = (const float*)d_in[6];
  float* out = (float*)d_out;

  char* p = (char*)d_ws;
  const size_t szQK = (size_t)2 * NPIX * CP * 2;
  unsigned short* QH = (unsigned short*)p; p += szQK;
  unsigned short* KH = (unsigned short*)p; p += szQK;
  unsigned short* VG = (unsigned short*)p; p += (size_t)2 * 80 * NPIX * 2;
  unsigned short* WH = (unsigned short*)p; p += (size_t)3 * 80 * 96 * 2;
  unsigned short* WL = (unsigned short*)p; p += (size_t)3 * 80 * 96 * 2;
  float* NUM = (float*)p; p += (size_t)SPLITS * 2 * 18 * NPIX * 4;   // 10.6 MB
  float* LPART = (float*)p; p += (size_t)SPLITS * 2 * NPIX * 4;      // 0.6 MB

  wprep_kernel<<<(3 * 80 * 96 + 255) / 256, 256, 0, stream>>>(Wq, Wk, Wv, WH, WL);
  qkv_kernel<<<1152, 64, 0, stream>>>(x, WH, WL, bq, bk, bv, QH, KH, VG);
  flash_kernel<<<768, 256, 0, stream>>>(x, QH, KH, VG, NUM, LPART);
  combine_pool_kernel<<<(2 * 18 * (NPIX / 4) + 255) / 256, 256, 0, stream>>>(
      NUM, LPART, out);
}

// Round 14
// 149.653 us; speedup vs baseline: 1.1456x; 1.1456x over previous
//
#include <hip/hip_runtime.h>

#define NPIX 9216
#define CIN 72
#define CP 96
#define SPLITS 8
#define JCHUNK (NPIX / SPLITS)   // 1152
#define JTILES (JCHUNK / 64)     // 18
// p = exp2(s*log2e - 32*log2e)  (fixed softmax shift 32; safe to s<120)
#define L2E   1.44269504088896f
#define EXPB  46.1662413084468f

typedef __attribute__((ext_vector_type(8))) short bf16x8;
typedef __attribute__((ext_vector_type(8))) _Float16 f16x8;
typedef __attribute__((ext_vector_type(4))) float f32x4;

#define MFMA_BF16(A,B,C) __builtin_amdgcn_mfma_f32_16x16x32_bf16(A,B,C,0,0,0)
#define MFMA_F16(A,B,C)  __builtin_amdgcn_mfma_f32_16x16x32_f16(A,B,C,0,0,0)

static __device__ __forceinline__ unsigned short f2bf(float f) {
  unsigned u = __float_as_uint(f);
  u += 0x7fffu + ((u >> 16) & 1u);
  return (unsigned short)(u >> 16);
}
static __device__ __forceinline__ float bf2f(unsigned short h) {
  return __uint_as_float(((unsigned)h) << 16);
}
static __device__ __forceinline__ unsigned short f2h(float f) {
  _Float16 h = (_Float16)f;
  return *(unsigned short*)&h;
}
// pack trunc-bf16 of (lo,hi) into one dword: [lo.hi16 | hi.hi16]
static __device__ __forceinline__ unsigned pack_bf_trunc(float lo, float hi) {
  return (__float_as_uint(lo) >> 16) | (__float_as_uint(hi) & 0xffff0000u);
}
// async global->LDS DMA, 16B per lane; lds dest = uniform base + lane*16
static __device__ __forceinline__ void load_lds16(const unsigned short* g,
                                                  unsigned short* l) {
  __builtin_amdgcn_global_load_lds(
      (const __attribute__((address_space(1))) unsigned int*)g,
      (__attribute__((address_space(3))) unsigned int*)l, 16, 0, 0);
}

// ---------------------------------------------------------------------------
// Kernel 0: W prep — split-bf16 (hi/lo) of Wq/Wk/Wv, padded to [80][96].
// ---------------------------------------------------------------------------
__global__ __launch_bounds__(256) void wprep_kernel(
    const float* __restrict__ Wq, const float* __restrict__ Wk,
    const float* __restrict__ Wv,
    unsigned short* __restrict__ WH, unsigned short* __restrict__ WL)
{
  int id = blockIdx.x * 256 + threadIdx.x;
  if (id >= 3 * 80 * 96) return;
  int mat = id / (80 * 96);
  int rem = id % (80 * 96);
  int d = rem / 96, c = rem % 96;
  const float* W = (mat == 0) ? Wq : (mat == 1) ? Wk : Wv;
  float v = (d < 72 && c < 72) ? W[d * 72 + c] : 0.f;
  unsigned short hi = f2bf(v);
  WH[id] = hi;
  WL[id] = f2bf(v - bf2f(hi));
}

// ---------------------------------------------------------------------------
// Kernel 1 (v2): QKV projection, mat-split — 192-thread blocks (3 waves),
// ONE WAVE PER MATRIX sharing a cooperatively-staged 16-px X strip.
// 3456 total waves (was 1152): 3.4 waves/SIMD hides the W-load latency that
// starved the one-wave-per-block version (1.1 waves/SIMD, 135 dep MFMAs).
// obuf is wave-private -> transpose needs no barriers (lgkmcnt only).
// V channel 72 = 1.0 (ones-row): flash PV computes L for free.
// ---------------------------------------------------------------------------
#define XTS 104   // LDS row stride (ushorts), 208 B

__global__ __launch_bounds__(192) void qkv_kernel(
    const float* __restrict__ x,
    const unsigned short* __restrict__ WH, const unsigned short* __restrict__ WL,
    const float* __restrict__ bq, const float* __restrict__ bk,
    const float* __restrict__ bv,
    unsigned short* __restrict__ QH, unsigned short* __restrict__ KH,
    unsigned short* __restrict__ VG)
{
  __shared__ __align__(16) unsigned short xth[16 * XTS];
  __shared__ __align__(16) unsigned short xtl[16 * XTS];
  __shared__ __align__(16) unsigned short obuf[2][16 * XTS];  // Q,K wave slices

  const int t    = threadIdx.x;
  const int w    = t >> 6;           // 0=Q, 1=K, 2=V
  const int lane = t & 63;
  const int quad = lane >> 4;
  const int l15  = lane & 15;
  const int bid  = blockIdx.x;
  const int b    = bid / 576;
  const int n0   = (bid % 576) * 16;

  // stage X strip cooperatively (192 threads), float4 loads, split-bf16,
  // transposed to [px][c]
  for (int e = t; e < 288; e += 192) {
    int c = e >> 2, f4 = (e & 3) * 4;
    float4 xv = *(const float4*)(x + ((size_t)b * CIN + c) * NPIX + n0 + f4);
    float vv[4] = {xv.x, xv.y, xv.z, xv.w};
#pragma unroll
    for (int k = 0; k < 4; ++k) {
      unsigned short hi = f2bf(vv[k]);
      xth[(f4 + k) * XTS + c] = hi;
      xtl[(f4 + k) * XTS + c] = f2bf(vv[k] - bf2f(hi));
    }
  }
  for (int e = t; e < 24 * 16; e += 192) {
    int c = 72 + (e >> 4), px = e & 15;
    xth[px * XTS + c] = 0;
    xtl[px * XTS + c] = 0;
  }
  __syncthreads();

  // B-operand fragments (n = l15 = px, k = quad*8+j)
  bf16x8 xbh[3], xbl[3];
#pragma unroll
  for (int ks = 0; ks < 3; ++ks) {
    int off = l15 * XTS + ks * 32 + quad * 8;
    xbh[ks] = *(const bf16x8*)(xth + off);
    xbl[ks] = *(const bf16x8*)(xtl + off);
  }

  // this wave's matrix
  const unsigned short* wh = WH + w * 80 * 96;
  const unsigned short* wl = WL + w * 80 * 96;
  const float* bias = (w == 0) ? bq : (w == 1) ? bk : bv;

  f32x4 acc[5];
#pragma unroll
  for (int dm = 0; dm < 5; ++dm) {
    acc[dm] = (f32x4){0.f, 0.f, 0.f, 0.f};
#pragma unroll
    for (int ks = 0; ks < 3; ++ks) {
      bf16x8 ah = *(const bf16x8*)(wh + (dm * 16 + l15) * 96 + ks * 32 + quad * 8);
      bf16x8 al = *(const bf16x8*)(wl + (dm * 16 + l15) * 96 + ks * 32 + quad * 8);
      acc[dm] = MFMA_BF16(ah, xbh[ks], acc[dm]);
      acc[dm] = MFMA_BF16(ah, xbl[ks], acc[dm]);
      acc[dm] = MFMA_BF16(al, xbh[ks], acc[dm]);
    }
  }

  if (w < 2) {
    // Q/K: bias + fp16, transpose via wave-private obuf (no barrier needed),
    // coalesced uint4 stores (cols 9..11 = zero pad)
    unsigned short* ob = obuf[w];
#pragma unroll
    for (int dm = 0; dm < 5; ++dm)
#pragma unroll
      for (int r = 0; r < 4; ++r) {
        int d = dm * 16 + quad * 4 + r;
        float v = acc[dm][r] + (d < 72 ? bias[d] : 0.f);
        ob[l15 * XTS + d] = f2h(v);
      }
    unsigned short* outp = (w == 0) ? QH : KH;
    const size_t obase = ((size_t)b * NPIX + n0) * CP;
    uint4 z; z.x = z.y = z.z = z.w = 0u;
    for (int f = lane; f < 192; f += 64) {
      int row = f / 12, col = f % 12;
      *(uint4*)(outp + obase + (size_t)row * CP + col * 8) =
          (col < 10) ? *(const uint4*)(ob + row * XTS + col * 8) : z;
    }
  } else {
    // V: bias + bf16, store [c][n] direct; rows 72..79: ones-row + zeros
#pragma unroll
    for (int dm = 0; dm < 5; ++dm)
#pragma unroll
      for (int r = 0; r < 4; ++r) {
        int d = dm * 16 + quad * 4 + r;
        float v = (d < 72) ? acc[dm][r] + bias[d] : (d == 72 ? 1.0f : 0.f);
        VG[((size_t)b * 80 + d) * NPIX + n0 + l15] = f2bf(v);
      }
  }
}

// ---------------------------------------------------------------------------
// Kernel 2: fused flash attention + pooling epilogue — R12 verbatim (best
// measured: 75.7 us). K via global_load_lds DMA (KSP=96 flat; measured
// FASTER than manual KSP=104 despite layout: DMA removes staging loads/
// writes/VALU and keeps loads in flight across the barrier — R13 A/B).
// V staged manually (VSP=72 conflict-free vf). O^T PV + ones-row L.
// Epilogue: fused factor-4 pooling -> NUM fp32. Grid 768; waves=3.
// ---------------------------------------------------------------------------
#define KSP 96    // k tile stride (ushorts) — flat, DMA-compatible
#define VSP 72    // v tile stride
#define PSP 72    // p tile stride

__global__ __launch_bounds__(256, 3) void flash_kernel(
    const float* __restrict__ x,
    const unsigned short* __restrict__ QH, const unsigned short* __restrict__ KH,
    const unsigned short* __restrict__ VG,
    float* __restrict__ NUM, float* __restrict__ LPART)
{
  __shared__ __align__(16) unsigned short ls_kh[64 * KSP];   // 12,288 B
  __shared__ __align__(16) unsigned short ls_vs[80 * VSP];   // 11,520 B
  __shared__ __align__(16) unsigned short ps[4][48 * PSP];   // 27,648 B

  const int t    = threadIdx.x;
  const int w    = t >> 6;
  const int lane = t & 63;
  const int quad = lane >> 4;
  const int l15  = lane & 15;

  const int bid  = blockIdx.x;
  const int sp   = bid & 7;          // split == XCD id (round-robin dispatch)
  const int slot = bid >> 3;
  const int b    = slot / 48;
  const int it   = slot % 48;
  const int i0w  = it * 192 + w * 48;

  // Q fragments (B-operand of S^T scores: n=l15=i, k=quad*8+c)
  f16x8 qh[3][3];
#pragma unroll
  for (int mi = 0; mi < 3; ++mi)
#pragma unroll
    for (int ks = 0; ks < 3; ++ks) {
      size_t off = ((size_t)b * NPIX + i0w + mi * 16 + l15) * CP + ks * 32 + quad * 8;
      qh[mi][ks] = *(const f16x8*)(QH + off);
    }

  f32x4 oacc[3][5];   // O^T[c][i]: c = nt*16+quad*4+r, i = mi*16+l15
#pragma unroll
  for (int mi = 0; mi < 3; ++mi)
#pragma unroll
    for (int nt = 0; nt < 5; ++nt) oacc[mi][nt] = (f32x4){0.f, 0.f, 0.f, 0.f};

  unsigned short* psw = ps[w];

  const unsigned short* kpg = KH + ((size_t)b * NPIX + sp * JCHUNK) * CP;
  const unsigned short* vpg = VG + (size_t)b * 80 * NPIX + sp * JCHUNK;

  for (int jt = 0; jt < JTILES; ++jt, kpg += 64 * CP, vpg += 64) {
    // ---- K tile: async DMA (12 chunks of 1024B; 3 per wave) ----
#pragma unroll
    for (int k = 0; k < 3; ++k) {
      int chunk = w + k * 4;
      load_lds16(kpg + chunk * 512 + lane * 8, ls_kh + chunk * 512);
    }
    // ---- V tile: manual staging (VSP=72 pad for conflict-free vf) ----
    for (int idx = t; idx < 640; idx += 256) {
      int r = idx >> 3, c = idx & 7;
      *(uint4*)(ls_vs + r * VSP + c * 8) =
          *(const uint4*)(vpg + (size_t)r * NPIX + c * 8);
    }
    __syncthreads();   // drains vmcnt (DMA + V loads) + lgkmcnt

    // ---- S^T scores (K from LDS) -> exp -> packed b64 P write ----
#pragma unroll
    for (int tj = 0; tj < 4; ++tj) {
      f16x8 fkh[3];
#pragma unroll
      for (int ks = 0; ks < 3; ++ks)
        fkh[ks] = *(const f16x8*)(ls_kh + (tj * 16 + l15) * KSP + ks * 32 + quad * 8);
#pragma unroll
      for (int mi = 0; mi < 3; ++mi) {
        f32x4 s = (f32x4){0.f, 0.f, 0.f, 0.f};
        s = MFMA_F16(fkh[0], qh[mi][0], s);   // A=K (m=j), B=Q (n=i)
        s = MFMA_F16(fkh[1], qh[mi][1], s);
        s = MFMA_F16(fkh[2], qh[mi][2], s);
        float p0 = __builtin_amdgcn_exp2f(__builtin_fmaf(s[0], L2E, -EXPB));
        float p1 = __builtin_amdgcn_exp2f(__builtin_fmaf(s[1], L2E, -EXPB));
        float p2 = __builtin_amdgcn_exp2f(__builtin_fmaf(s[2], L2E, -EXPB));
        float p3 = __builtin_amdgcn_exp2f(__builtin_fmaf(s[3], L2E, -EXPB));
        uint2 pk;
        pk.x = pack_bf_trunc(p0, p1);
        pk.y = pack_bf_trunc(p2, p3);
        *(uint2*)(psw + (mi * 16 + l15) * PSP + tj * 16 + quad * 4) = pk;
      }
    }

    // ---- PV as O^T: A = V (LDS, m=c incl. ones-row 72), B = P (own-wave) ----
#pragma unroll
    for (int js = 0; js < 2; ++js) {
      bf16x8 pf[3];
#pragma unroll
      for (int mi = 0; mi < 3; ++mi)
        pf[mi] = *(const bf16x8*)(psw + (mi * 16 + l15) * PSP + js * 32 + quad * 8);
#pragma unroll
      for (int nt = 0; nt < 5; ++nt) {
        bf16x8 vf = *(const bf16x8*)(ls_vs + (nt * 16 + l15) * VSP + js * 32 + quad * 8);
#pragma unroll
        for (int mi = 0; mi < 3; ++mi)
          oacc[mi][nt] = MFMA_BF16(vf, pf[mi], oacc[mi][nt]);
      }
    }
    __syncthreads();   // all K/V LDS reads done before next staging
  }

  // ---- epilogue: L from ones-row; fused factor-4 pooling -> NUM fp32 ----
  const size_t sb = (size_t)(sp * 2 + b);
#pragma unroll
  for (int mi = 0; mi < 3; ++mi) {
    const int i = i0w + mi * 16 + l15;
    if (quad == 2)   // c = 72: the ones-row -> L
      LPART[sb * NPIX + i] = oacc[mi][4][0];
#pragma unroll
    for (int nt = 0; nt < 5; ++nt) {
      int c0 = nt * 16 + quad * 4;
      if (c0 < 72) {
        float num = 0.f;
#pragma unroll
        for (int r = 0; r < 4; ++r)
          num = __builtin_fmaf(x[((size_t)b * CIN + c0 + r) * NPIX + i],
                               oacc[mi][nt][r], num);
        NUM[(sb * 18 + (c0 >> 2)) * NPIX + i] = num;   // g = nt*4+quad
      }
    }
  }
}

// ---------------------------------------------------------------------------
// Kernel 3: combine splits: out = (sum_s NUM_s) / (sum_s L_s). Trivial.
// ---------------------------------------------------------------------------
__global__ __launch_bounds__(256) void combine_pool_kernel(
    const float* __restrict__ NUM, const float* __restrict__ LPART,
    float* __restrict__ out)
{
  int id = blockIdx.x * 256 + threadIdx.x;
  if (id >= 2 * 18 * (NPIX / 4)) return;
  int n = (id % (NPIX / 4)) * 4;
  int rest = id / (NPIX / 4);       // = b*18 + g
  int g = rest % 18, b = rest / 18;

  float4 A = make_float4(0.f, 0.f, 0.f, 0.f);
  float4 L = make_float4(0.f, 0.f, 0.f, 0.f);
#pragma unroll
  for (int s = 0; s < SPLITS; ++s) {
    size_t sb = (size_t)(s * 2 + b);
    float4 a = *(const float4*)(NUM + (sb * 18 + g) * NPIX + n);
    float4 l = *(const float4*)(LPART + sb * NPIX + n);
    A.x += a.x; A.y += a.y; A.z += a.z; A.w += a.w;
    L.x += l.x; L.y += l.y; L.z += l.z; L.w += l.w;
  }
  float4 r;
  r.x = A.x / L.x; r.y = A.y / L.y; r.z = A.z / L.z; r.w = A.w / L.w;
  *(float4*)(out + (size_t)id * 4) = r;
}

// ---------------------------------------------------------------------------
extern "C" void kernel_launch(void* const* d_in, const int* in_sizes, int n_in,
                              void* d_out, int out_size, void* d_ws, size_t ws_size,
                              hipStream_t stream) {
  const float* x  = (const float*)d_in[0];
  const float* Wq = (const float*)d_in[1];
  const float* bq = (const float*)d_in[2];
  const float* Wk = (const float*)d_in[3];
  const float* bk = (const float*)d_in[4];
  const float* Wv = (const float*)d_in[5];
  const float* bv = (const float*)d_in[6];
  float* out = (float*)d_out;

  char* p = (char*)d_ws;
  const size_t szQK = (size_t)2 * NPIX * CP * 2;
  unsigned short* QH = (unsigned short*)p; p += szQK;
  unsigned short* KH = (unsigned short*)p; p += szQK;
  unsigned short* VG = (unsigned short*)p; p += (size_t)2 * 80 * NPIX * 2;
  unsigned short* WH = (unsigned short*)p; p += (size_t)3 * 80 * 96 * 2;
  unsigned short* WL = (unsigned short*)p; p += (size_t)3 * 80 * 96 * 2;
  float* NUM = (float*)p; p += (size_t)SPLITS * 2 * 18 * NPIX * 4;   // 10.6 MB
  float* LPART = (float*)p; p += (size_t)SPLITS * 2 * NPIX * 4;      // 0.6 MB

  wprep_kernel<<<(3 * 80 * 96 + 255) / 256, 256, 0, stream>>>(Wq, Wk, Wv, WH, WL);
  qkv_kernel<<<1152, 192, 0, stream>>>(x, WH, WL, bq, bk, bv, QH, KH, VG);
  flash_kernel<<<768, 256, 0, stream>>>(x, QH, KH, VG, NUM, LPART);
  combine_pool_kernel<<<(2 * 18 * (NPIX / 4) + 255) / 256, 256, 0, stream>>>(
      NUM, LPART, out);
}